// Round 4
// baseline (107.593 us; speedup 1.0000x reference)
//
#include <hip/hip_runtime.h>

typedef __attribute__((ext_vector_type(8))) short bf8;
typedef __attribute__((ext_vector_type(4))) float f4;

static __device__ __forceinline__ short bfr(float x) {
    union { float f; unsigned u; } v; v.f = x;
    return (short)((v.u + 0x7FFF + ((v.u >> 16) & 1)) >> 16);  // RNE
}
static __device__ __forceinline__ float bf2f(short s) {
    union { float f; unsigned u; } v; v.u = ((unsigned)(unsigned short)s) << 16;
    return v.f;
}
static __device__ __forceinline__ bf8 pack8(float4 a, float4 b) {
    bf8 r;
    r[0] = bfr(a.x); r[1] = bfr(a.y); r[2] = bfr(a.z); r[3] = bfr(a.w);
    r[4] = bfr(b.x); r[5] = bfr(b.y); r[6] = bfr(b.z); r[7] = bfr(b.w);
    return r;
}

// Single fully-fused kernel. Grid 256 x 512 thr (1 block/CU, 8 waves).
// Block = (b = blk>>6, 8-row q-tile i0). No workspace, no second launch:
// uses qk = (q @ Wk) @ keys^T + (q . bk), so the k-projection never needs to
// be materialized across blocks. Per block:
//   A: q = queries_rows @ Wq^T + bq   (16 MFMA/wave, B-frags from global Wq)
//   B: t = q @ Wk                     (16 MFMA/wave, Wk column gather, L2-hot)
//      + qbk[i] = dot(q[i], bk)
//   C: qk = t @ keys^T (fp32 keys packed on the fly), qr = q @ rel_emb^T,
//      3-barrier softmax (measured best structure from prior session).
// A-rows duplicated (n15&7) so the 16x16 MFMA tile carries 8 real rows; dup
// lanes hit identical cache lines. Do NOT shrink the 8-row i-tile (R2: 4-row
// tile doubled K L2 traffic, attn 18->52 us).
__global__ __launch_bounds__(512) void fused_attn(
    const float* __restrict__ queries, const float* __restrict__ keys,
    const int* __restrict__ relations, const float* __restrict__ Wq,
    const float* __restrict__ bq, const float* __restrict__ Wk,
    const float* __restrict__ bk, const float* __restrict__ rel_emb,
    float* __restrict__ out)
{
    __shared__ short q_l[8][264];   // q rows bf16 (stride 264: 16B-aligned rows)
    __shared__ short t_l[8][264];   // t rows bf16
    __shared__ float qr_l[16][112];
    __shared__ float red_m[16][8];
    __shared__ float red_s[16][8];
    __shared__ float qbk_l[8];

    int blk = blockIdx.x;
    int b = blk >> 6;
    int i0 = (blk & 63) * 8;
    int gi0 = b * 512 + i0;
    int w = threadIdx.x >> 6;        // 8 waves
    int lane = threadIdx.x & 63;
    int n15 = lane & 15, quad = lane >> 4;

    // prefetch relations early (HBM ~900cy, hides under phases A/B).
    // C row m=quad*4+reg -> real row (quad&1)*4+reg
    const int* rb = relations + (gi0 + (quad & 1) * 4) * 512 + w * 64 + n15;
    int rv[4][4];
#pragma unroll
    for (int reg = 0; reg < 4; reg++)
#pragma unroll
        for (int nt = 0; nt < 4; nt++)
            rv[nt][reg] = rb[reg * 512 + nt * 16];

    f4 z = {0.f, 0.f, 0.f, 0.f};

    // ---- Phase A: q-proj. Wave w -> cols w*32..w*32+31 ----
    int arow = gi0 + (n15 & 7);      // rows 8..15 duplicate 0..7
    bf8 aq[8];
#pragma unroll
    for (int kk = 0; kk < 8; kk++) {
        const float4* ap = (const float4*)(queries + arow * 256 + kk * 32 + quad * 8);
        aq[kk] = pack8(ap[0], ap[1]);
    }
    {
        f4 cq[2] = {z, z};
#pragma unroll
        for (int nt = 0; nt < 2; nt++) {
            int col = w * 32 + nt * 16 + n15;
            const float* wqr = Wq + col * 256 + quad * 8;
#pragma unroll
            for (int kk = 0; kk < 8; kk++) {
                const float4* bp = (const float4*)(wqr + kk * 32);
                cq[nt] = __builtin_amdgcn_mfma_f32_16x16x32_bf16(aq[kk], pack8(bp[0], bp[1]),
                                                                 cq[nt], 0, 0, 0);
            }
        }
        if (quad < 2) {
#pragma unroll
            for (int nt = 0; nt < 2; nt++) {
                int col = w * 32 + nt * 16 + n15;
                float bv = bq[col];
#pragma unroll
                for (int reg = 0; reg < 4; reg++)
                    q_l[quad * 4 + reg][col] = bfr(cq[nt][reg] + bv);
            }
        }
    }
    __syncthreads();

    // ---- Phase B: t = q @ Wk (contract over proj dim n) ----
    bf8 aQ[8];  // q as A-frag (also reused for qr in phase C)
#pragma unroll
    for (int kk = 0; kk < 8; kk++)
        aQ[kk] = *(const bf8*)&q_l[n15 & 7][kk * 32 + quad * 8];

    {
        f4 ct[2] = {z, z};
#pragma unroll
        for (int nt = 0; nt < 2; nt++) {
            int h = w * 32 + nt * 16 + n15;
#pragma unroll
            for (int kk = 0; kk < 8; kk++) {
                // B[h][n-slice] = Wk[n][h]: column gather, 64B-coalesced per
                // 16-lane group, fully L2-resident (Wk = 256 KB).
                const float* wp = Wk + (kk * 32 + quad * 8) * 256 + h;
                bf8 bf_;
#pragma unroll
                for (int j = 0; j < 8; j++) bf_[j] = bfr(wp[j * 256]);
                ct[nt] = __builtin_amdgcn_mfma_f32_16x16x32_bf16(aQ[kk], bf_, ct[nt], 0, 0, 0);
            }
        }
        if (quad < 2) {
#pragma unroll
            for (int nt = 0; nt < 2; nt++) {
                int h = w * 32 + nt * 16 + n15;
#pragma unroll
                for (int reg = 0; reg < 4; reg++)
                    t_l[quad * 4 + reg][h] = bfr(ct[nt][reg]);
            }
        }
    }

    // qbk[i] = dot(q[i], bk): wave w handles row w (4 elems/lane, 64-lane reduce)
    {
        const short* qp = &q_l[w][lane * 4];
        float4 bkv = *(const float4*)(bk + lane * 4);
        float a0 = bf2f(qp[0]) * bkv.x + bf2f(qp[1]) * bkv.y +
                   bf2f(qp[2]) * bkv.z + bf2f(qp[3]) * bkv.w;
#pragma unroll
        for (int d = 1; d <= 32; d <<= 1) a0 += __shfl_xor(a0, d, 64);
        if (lane == 0) qbk_l[w] = a0;
    }
    __syncthreads();

    // ---- Phase C: qk = t @ keys^T, qr = q @ rel_emb^T, softmax ----
    bf8 aT[8];
#pragma unroll
    for (int kk = 0; kk < 8; kk++)
        aT[kk] = *(const bf8*)&t_l[n15 & 7][kk * 32 + quad * 8];

    f4 c[4] = {z, z, z, z};
#pragma unroll
    for (int nt = 0; nt < 4; nt++) {
        int krow = b * 512 + w * 64 + nt * 16 + n15;
        const float* kr = keys + krow * 256 + quad * 8;
#pragma unroll
        for (int kk = 0; kk < 8; kk++) {
            const float4* kp = (const float4*)(kr + kk * 32);
            c[nt] = __builtin_amdgcn_mfma_f32_16x16x32_bf16(aT[kk], pack8(kp[0], kp[1]),
                                                            c[nt], 0, 0, 0);
        }
    }

    if (w < 7) {  // qr: rel rows w*16..w*16+15, rows >= 99 are zero
        f4 cr = z;
        int rrow = w * 16 + n15;
        bool valid = rrow < 99;
        const float* rp = rel_emb + (valid ? rrow : 0) * 256 + quad * 8;
#pragma unroll
        for (int kk = 0; kk < 8; kk++) {
            const float4* rpp = (const float4*)(rp + kk * 32);
            float4 x0 = rpp[0], x1 = rpp[1];
            if (!valid) { x0 = make_float4(0.f, 0.f, 0.f, 0.f); x1 = x0; }
            cr = __builtin_amdgcn_mfma_f32_16x16x32_bf16(aQ[kk], pack8(x0, x1), cr, 0, 0, 0);
        }
#pragma unroll
        for (int reg = 0; reg < 4; reg++)
            qr_l[quad * 4 + reg][rrow] = cr[reg];  // dup rows get dup values
    }
    __syncthreads();

    const float scale = 0.0625f;  // 1/sqrt(256)
    float lg[4][4];
#pragma unroll
    for (int nt = 0; nt < 4; nt++)
#pragma unroll
        for (int reg = 0; reg < 4; reg++)
            lg[nt][reg] = (c[nt][reg] + qr_l[quad * 4 + reg][rv[nt][reg]] +
                           qbk_l[(quad & 1) * 4 + reg]) * scale;

    float pm[4];
#pragma unroll
    for (int reg = 0; reg < 4; reg++) {
        float m = fmaxf(fmaxf(lg[0][reg], lg[1][reg]), fmaxf(lg[2][reg], lg[3][reg]));
#pragma unroll
        for (int d = 1; d <= 8; d <<= 1) m = fmaxf(m, __shfl_xor(m, d, 64));
        pm[reg] = m;
    }
    if (n15 == 0)
#pragma unroll
        for (int reg = 0; reg < 4; reg++) red_m[quad * 4 + reg][w] = pm[reg];
    __syncthreads();
    float M[4];
#pragma unroll
    for (int reg = 0; reg < 4; reg++) {
        f4 a0 = *(const f4*)&red_m[quad * 4 + reg][0];
        f4 a1 = *(const f4*)&red_m[quad * 4 + reg][4];
        M[reg] = fmaxf(fmaxf(fmaxf(a0[0], a0[1]), fmaxf(a0[2], a0[3])),
                       fmaxf(fmaxf(a1[0], a1[1]), fmaxf(a1[2], a1[3])));
    }

    float ps[4];
#pragma unroll
    for (int reg = 0; reg < 4; reg++) {
        float s = 0.f;
#pragma unroll
        for (int nt = 0; nt < 4; nt++) {
            float e = __expf(lg[nt][reg] - M[reg]);
            lg[nt][reg] = e;
            s += e;
        }
#pragma unroll
        for (int d = 1; d <= 8; d <<= 1) s += __shfl_xor(s, d, 64);
        ps[reg] = s;
    }
    if (n15 == 0)
#pragma unroll
        for (int reg = 0; reg < 4; reg++) red_s[quad * 4 + reg][w] = ps[reg];
    __syncthreads();
    float inv[4];
#pragma unroll
    for (int reg = 0; reg < 4; reg++) {
        f4 a0 = *(const f4*)&red_s[quad * 4 + reg][0];
        f4 a1 = *(const f4*)&red_s[quad * 4 + reg][4];
        inv[reg] = 1.f / (a0[0] + a0[1] + a0[2] + a0[3] + a1[0] + a1[1] + a1[2] + a1[3]);
    }

    if (quad < 2) {  // rows 0..7 real; quads 2,3 are duplicates
        float* ob = out + (gi0 + quad * 4) * 512 + w * 64 + n15;
#pragma unroll
        for (int reg = 0; reg < 4; reg++)
#pragma unroll
            for (int nt = 0; nt < 4; nt++)
                ob[reg * 512 + nt * 16] = lg[nt][reg] * inv[reg];
    }
}

extern "C" void kernel_launch(void* const* d_in, const int* in_sizes, int n_in,
                              void* d_out, int out_size, void* d_ws, size_t ws_size,
                              hipStream_t stream) {
    const float* queries = (const float*)d_in[0];
    const float* keys = (const float*)d_in[1];
    const int* relations = (const int*)d_in[2];
    const float* Wq = (const float*)d_in[3];
    const float* bq = (const float*)d_in[4];
    const float* Wk = (const float*)d_in[5];
    const float* bk = (const float*)d_in[6];
    const float* rel_emb = (const float*)d_in[7];
    float* out = (float*)d_out;

    hipLaunchKernelGGL(fused_attn, dim3(256), dim3(512), 0, stream,
                       queries, keys, relations, Wq, bq, Wk, bk, rel_emb, out);
}